// Round 11
// baseline (19032.144 us; speedup 1.0000x reference)
//
#include <hip/hip_runtime.h>
#include <hip/hip_fp16.h>

typedef unsigned int u32;
typedef _Float16 h2v __attribute__((ext_vector_type(2)));

#define TSLEN 512
#define N0 306
#define N1 204
#define D0 370
#define D1 510
#define D2 206

// ws u32/f32 offsets (round-7 verified layout)
#define OFF_WA  0          // uint4[48][918]  layer-A planes (plane-major, lane-coalesced)
#define OFF_WB  176256     // uint4[48][816]  layer-B planes
#define OFF_WC1 332928     // f32[2][208]
#define OFF_WC2 333344
#define OFF_WCT 333760
#define OFF_BA  334176     // float4[306]
#define OFF_BB  335400     // float4[204]
#define OFF_B2  336216     // float4[2]
// total 336224 dwords = 1.34 MB

__device__ __forceinline__ u32 packh2(float a, float b) {
  __half2 h = __floats2half2_rn(a, b);
  return __builtin_bit_cast(u32, h);
}

__device__ __forceinline__ float dot2(u32 w, u32 xx, float acc) {
  return __builtin_amdgcn_fdot2(__builtin_bit_cast(h2v, w), __builtin_bit_cast(h2v, xx), acc, false);
}

__device__ __forceinline__ float cellact3(float a1, float a2, float at, float4 b) {
  float t1 = tanhf(a1 + b.x);
  float t2 = tanhf(a2 + b.y);
  float tv = 1.f / (1.f + __expf(-(at + b.z)));   // sigmoid(tb - ta)
  return t1 * (1.f - tv) + tv * t2;
}

// Issue 8 coalesced uint4 loads (stride STR uint4s) into a register buffer.
template<int STR>
__device__ __forceinline__ void load8(const uint4* __restrict__ p, uint4 (&w)[8]) {
  #pragma unroll
  for (int j = 0; j < 8; ++j) w[j] = p[j * STR];
}
// Consume a register buffer against reg-held x (32 fdot2).
__device__ __forceinline__ float consume8(const uint4 (&w)[8], const uint4 (&xv)[8], float a) {
  #pragma unroll
  for (int j = 0; j < 8; ++j) {
    a = dot2(w[j].x, xv[j].x, a);
    a = dot2(w[j].y, xv[j].y, a);
    a = dot2(w[j].z, xv[j].z, a);
    a = dot2(w[j].w, xv[j].w, a);
  }
  return a;
}

__global__ __launch_bounds__(256) void prep_kernel(
    const float* __restrict__ f1w0, const float* __restrict__ f2w0,
    const float* __restrict__ taw0, const float* __restrict__ tbw0, const int* __restrict__ m0,
    const float* __restrict__ f1b0, const float* __restrict__ f2b0,
    const float* __restrict__ tab0, const float* __restrict__ tbb0,
    const float* __restrict__ f1w1, const float* __restrict__ f2w1,
    const float* __restrict__ taw1, const float* __restrict__ tbw1, const int* __restrict__ m1,
    const float* __restrict__ f1b1, const float* __restrict__ f2b1,
    const float* __restrict__ tab1, const float* __restrict__ tbb1,
    const float* __restrict__ f1w2, const float* __restrict__ f2w2,
    const float* __restrict__ taw2, const float* __restrict__ tbw2, const int* __restrict__ m2,
    const float* __restrict__ f1b2, const float* __restrict__ f2b2,
    const float* __restrict__ tab2, const float* __restrict__ tbb2,
    float* __restrict__ ws)
{
  int j = blockIdx.x * 256 + threadIdx.x;
  u32* W = (u32*)ws;
  if (j < 176256) {                       // layer A: [plane*16+jj][u*3+s] uint4, component c
    int q4 = j >> 2, c = j & 3;
    int jq = q4 / 918, us = q4 - jq * 918;
    int u = us / 3, s = us - u * 3;
    int plane = jq >> 4, jj = jq & 15;
    int p = s * 64 + jj * 4 + c;          // k-pair index in padded 384-k space
    int k0 = 2 * p, k1 = 2 * p + 1;
    float v0 = 0.f, v1 = 0.f;
    if (k0 < D0) {
      int i = u * D0 + k0;
      v0 = (plane == 0) ? f1w0[i] * (float)m0[i]
         : (plane == 1) ? f2w0[i] * (float)m0[i]
                        : tbw0[i] - taw0[i];
    }
    if (k1 < D0) {
      int i = u * D0 + k1;
      v1 = (plane == 0) ? f1w0[i] * (float)m0[i]
         : (plane == 1) ? f2w0[i] * (float)m0[i]
                        : tbw0[i] - taw0[i];
    }
    W[OFF_WA + j] = packh2(v0, v1);
    return;
  }
  j -= 176256;
  if (j < 156672) {                       // layer B: [plane*16+jj][u*4+s]
    int q4 = j >> 2, c = j & 3;
    int jq = q4 / 816, us = q4 - jq * 816;
    int u = us >> 2, s = us & 3;
    int plane = jq >> 4, jj = jq & 15;
    int p = s * 64 + jj * 4 + c;          // padded 512-k space
    int k0 = 2 * p, k1 = 2 * p + 1;
    float v0 = 0.f, v1 = 0.f;
    if (k0 < D1) {
      int i = u * D1 + k0;
      v0 = (plane == 0) ? f1w1[i] * (float)m1[i]
         : (plane == 1) ? f2w1[i] * (float)m1[i]
                        : tbw1[i] - taw1[i];
    }
    if (k1 < D1) {
      int i = u * D1 + k1;
      v1 = (plane == 0) ? f1w1[i] * (float)m1[i]
         : (plane == 1) ? f2w1[i] * (float)m1[i]
                        : tbw1[i] - taw1[i];
    }
    W[OFF_WB + j] = packh2(v0, v1);
    return;
  }
  j -= 156672;
  if (j < 416) {                          // layer C (fp32 [u][208])
    int u = j / 208, d = j - u * 208;
    float f1 = 0.f, f2 = 0.f, td = 0.f;
    if (d < D2) { int i = u * D2 + d; float m = (float)m2[i]; f1 = f1w2[i]*m; f2 = f2w2[i]*m; td = tbw2[i]-taw2[i]; }
    ws[OFF_WC1 + j] = f1; ws[OFF_WC2 + j] = f2; ws[OFF_WCT + j] = td;
    return;
  }
  j -= 416;
  if (j < 306) { ((float4*)(ws + OFF_BA))[j] = make_float4(f1b0[j], f2b0[j], tbb0[j] - tab0[j], 0.f); return; }
  j -= 306;
  if (j < 204) { ((float4*)(ws + OFF_BB))[j] = make_float4(f1b1[j], f2b1[j], tbb1[j] - tab1[j], 0.f); return; }
  j -= 204;
  if (j < 2)   { ((float4*)(ws + OFF_B2))[j] = make_float4(f1b2[j], f2b2[j], tbb2[j] - tab2[j], 0.f); return; }
}

// One block (1024 thr) = one batch row. Weights streamed from ws (L2-shared image)
// with a 2-deep register-double-buffered pipeline (wv0/wv1) + cross-phase prefetch:
// batch0 of each phase is issued during the preceding LDS-only phase, so its
// latency hides under barriers. __launch_bounds__(1024,4) -> 128-VGPR budget.
__global__ __launch_bounds__(1024, 4) void lnn_main(
    const float* __restrict__ x, const float* __restrict__ h0,
    const float* __restrict__ fcw, const float* __restrict__ fcb,
    const float* __restrict__ ws, float* __restrict__ out)
{
  __shared__ uint4 XA4[48];      // [x(64)|hi(306)|pad] as half2, 3 spans x 16 uint4
  __shared__ uint4 XB4[64];      // [hi(306)|hc(204)|pad], 4 spans x 16 uint4
  __shared__ float XB32[512];    // f32 copies: hi(306) | hc(204) | pad
  __shared__ float pA[918 * 3];
  __shared__ float pB[204 * 13];
  __shared__ float shm2[2];

  const int tid = threadIdx.x;
  const int row = blockIdx.x;

  const int sA_ = tid % 3;                  // A: tid = u*3 + s, tid < 918
  const int uB = tid >> 2, sB_ = tid & 3;   // B: tid = u*4 + s, tid < 816
  const int l15 = tid - 960, u2 = l15 & 1, ch = l15 >> 1;   // wave 15: layer C

  const uint4* __restrict__ WA4 = (const uint4*)((const u32*)ws + OFF_WA);
  const uint4* __restrict__ WB4 = (const uint4*)((const u32*)ws + OFF_WB);
  const float4* BA4 = (const float4*)(ws + OFF_BA);
  const float4* BB4 = (const float4*)(ws + OFF_BB);
  const float4* B24 = (const float4*)(ws + OFF_B2);

  __half* XAh = (__half*)XA4;
  __half* XBh = (__half*)XB4;

  float4 ba = make_float4(0.f,0.f,0.f,0.f), bb = make_float4(0.f,0.f,0.f,0.f);
  float hm0 = 0.f, hm1 = 0.f;

  if (tid < 306) ba = BA4[tid];
  if (tid < 204) bb = BB4[tid];
  if (tid >= 960) {
    hm0 = h0[(size_t)row * 512 + 510];
    hm1 = h0[(size_t)row * 512 + 511];
  }

  // ---- init LDS state ----
  if (tid < 306) {
    float v = h0[(size_t)row * 512 + tid];
    XAh[64 + tid] = __float2half(v);
  }
  if (tid < 204) {
    float v = h0[(size_t)row * 512 + 306 + tid];
    XBh[306 + tid] = __float2half(v);
    XB32[306 + tid] = v;
  }
  if (tid < 14) XAh[370 + tid] = __float2half(0.f);   // pad k 370..383
  if (tid >= 14 && tid < 16) XBh[510 + (tid - 14)] = __float2half(0.f);
  __syncthreads();

  // ---- pipeline register buffers ----
  uint4 wv0[8], wv1[8];
  if (tid < 918) load8<918>(WA4 + tid, wv0);   // A batch0 = (p0,h0)

  for (int t = 0; t < TSLEN; ++t) {
    // ---- phase 1: B-finish(t-1) on tid<204; x_t staging on tid 204..235 ----
    if (t > 0 && tid < 204) {
      int b = tid * 13;
      float a1 = pB[b+0] + pB[b+3] + pB[b+6] + pB[b+9];
      float a2 = pB[b+1] + pB[b+4] + pB[b+7] + pB[b+10];
      float at = pB[b+2] + pB[b+5] + pB[b+8] + pB[b+11];
      float hc = cellact3(a1, a2, at, bb);
      XB32[306 + tid] = hc;
      XBh[306 + tid] = __float2half(hc);
    } else if (tid >= 204 && tid < 236) {
      int i = tid - 204;
      float2 xv_ = *(const float2*)(x + ((size_t)row * TSLEN + t) * 64 + 2 * i);
      ((u32*)XA4)[i] = packh2(xv_.x, xv_.y);
    }
    __syncthreads();

    // ---- phase 2: A-partials (tid<918, pipelined) + lagged layer C (wave 15) ----
    if (tid < 918) {
      const uint4* wp = WA4 + tid;
      const uint4* xs = XA4 + sA_ * 16;
      uint4 xv[8];
      #pragma unroll
      for (int j = 0; j < 8; ++j) xv[j] = xs[j];               // x half0
      load8<918>(wp + (1 * 16) * 918, wv1);                    // b1=(p1,h0)
      float a1 = 0.f, a2 = 0.f, at = 0.f;
      a1 = consume8(wv0, xv, a1);
      load8<918>(wp + (2 * 16) * 918, wv0);                    // b2=(p2,h0)
      a2 = consume8(wv1, xv, a2);
      load8<918>(wp + (0 * 16 + 8) * 918, wv1);                // b3=(p0,h1)
      at = consume8(wv0, xv, at);
      load8<918>(wp + (1 * 16 + 8) * 918, wv0);                // b4=(p1,h1)
      #pragma unroll
      for (int j = 0; j < 8; ++j) xv[j] = xs[8 + j];           // x half1
      a1 = consume8(wv1, xv, a1);
      load8<918>(wp + (2 * 16 + 8) * 918, wv1);                // b5=(p2,h1)
      a2 = consume8(wv0, xv, a2);
      at = consume8(wv1, xv, at);
      pA[tid * 3 + 0] = a1; pA[tid * 3 + 1] = a2; pA[tid * 3 + 2] = at;
    } else if (tid >= 960 && t > 0) {
      float a1 = 0.f, a2 = 0.f, at = 0.f;
      #pragma unroll
      for (int j = 0; j < 7; ++j) {
        int d = ch * 7 + j;
        bool ok = d < 208;
        float w1 = ok ? ws[OFF_WC1 + u2 * 208 + d] : 0.f;
        float w2 = ok ? ws[OFF_WC2 + u2 * 208 + d] : 0.f;
        float wt = ok ? ws[OFF_WCT + u2 * 208 + d] : 0.f;
        float xv_ = (d < 204) ? XB32[306 + d] : (d == 204 ? hm0 : (d == 205 ? hm1 : 0.f));
        a1 = fmaf(w1, xv_, a1); a2 = fmaf(w2, xv_, a2); at = fmaf(wt, xv_, at);
      }
      #pragma unroll
      for (int m = 2; m <= 32; m <<= 1) {
        a1 += __shfl_xor(a1, m); a2 += __shfl_xor(a2, m); at += __shfl_xor(at, m);
      }
      float4 b2 = B24[u2];
      float hmn = cellact3(a1, a2, at, b2);
      float other = __shfl_xor(hmn, 1);
      hm0 = (u2 == 0) ? hmn : other;
      hm1 = (u2 == 0) ? other : hmn;
    }
    __syncthreads();

    // ---- phase 3: B batch0 prefetch + A-finish -> hi(t) ----
    if (tid < 816) load8<816>(WB4 + tid, wv0);                 // B b0=(p0,h0)
    if (tid < 306) {
      int b = tid * 9;
      float a1 = pA[b+0] + pA[b+3] + pA[b+6];
      float a2 = pA[b+1] + pA[b+4] + pA[b+7];
      float at = pA[b+2] + pA[b+5] + pA[b+8];
      float hi = cellact3(a1, a2, at, ba);
      XB32[tid] = hi;
      __half hh = __float2half(hi);
      XBh[tid] = hh;
      XAh[64 + tid] = hh;
    }
    __syncthreads();

    // ---- phase 4: B-partials (tid<816, pipelined) ----
    if (tid < 816) {
      const uint4* wp = WB4 + tid;
      const uint4* xs = XB4 + sB_ * 16;
      uint4 xv[8];
      #pragma unroll
      for (int j = 0; j < 8; ++j) xv[j] = xs[j];               // x half0
      load8<816>(wp + (1 * 16) * 816, wv1);                    // b1=(p1,h0)
      float a1 = 0.f, a2 = 0.f, at = 0.f;
      a1 = consume8(wv0, xv, a1);
      load8<816>(wp + (2 * 16) * 816, wv0);                    // b2=(p2,h0)
      a2 = consume8(wv1, xv, a2);
      load8<816>(wp + (0 * 16 + 8) * 816, wv1);                // b3=(p0,h1)
      at = consume8(wv0, xv, at);
      load8<816>(wp + (1 * 16 + 8) * 816, wv0);                // b4=(p1,h1)
      #pragma unroll
      for (int j = 0; j < 8; ++j) xv[j] = xs[8 + j];           // x half1
      a1 = consume8(wv1, xv, a1);
      load8<816>(wp + (2 * 16 + 8) * 816, wv1);                // b5=(p2,h1)
      a2 = consume8(wv0, xv, a2);
      at = consume8(wv1, xv, at);
      pB[uB * 13 + sB_ * 3 + 0] = a1;
      pB[uB * 13 + sB_ * 3 + 1] = a2;
      pB[uB * 13 + sB_ * 3 + 2] = at;
    }
    // prefetch next step's A batch0 (weights are step-invariant; latency hides
    // under the barrier + phase 1)
    if (tid < 918) load8<918>(WA4 + tid, wv0);
    __syncthreads();
  }

  // ---- epilogue ----
  if (tid < 204) {   // B-finish t=511 -> hc(511)
    int b = tid * 13;
    float a1 = pB[b+0] + pB[b+3] + pB[b+6] + pB[b+9];
    float a2 = pB[b+1] + pB[b+4] + pB[b+7] + pB[b+10];
    float at = pB[b+2] + pB[b+5] + pB[b+8] + pB[b+11];
    XB32[306 + tid] = cellact3(a1, a2, at, bb);
  }
  __syncthreads();
  if (tid >= 960) {  // hm(511) from hc(511) + hm(510)
    float a1 = 0.f, a2 = 0.f, at = 0.f;
    #pragma unroll
    for (int j = 0; j < 7; ++j) {
      int d = ch * 7 + j;
      bool ok = d < 208;
      float w1 = ok ? ws[OFF_WC1 + u2 * 208 + d] : 0.f;
      float w2 = ok ? ws[OFF_WC2 + u2 * 208 + d] : 0.f;
      float wt = ok ? ws[OFF_WCT + u2 * 208 + d] : 0.f;
      float xv_ = (d < 204) ? XB32[306 + d] : (d == 204 ? hm0 : (d == 205 ? hm1 : 0.f));
      a1 = fmaf(w1, xv_, a1); a2 = fmaf(w2, xv_, a2); at = fmaf(wt, xv_, at);
    }
    #pragma unroll
    for (int m = 2; m <= 32; m <<= 1) {
      a1 += __shfl_xor(a1, m); a2 += __shfl_xor(a2, m); at += __shfl_xor(at, m);
    }
    float4 b2 = B24[u2];
    float hmn = cellact3(a1, a2, at, b2);
    if (l15 < 2) shm2[u2] = hmn;
  }
  __syncthreads();

  if (tid < 2) {
    int o = tid;
    out[(size_t)row * 2 + o] = shm2[0] * fcw[o * 2 + 0] + shm2[1] * fcw[o * 2 + 1] + fcb[o];
  }
  if (tid < 512) {
    float v = (tid < 510) ? XB32[tid] : shm2[tid - 510];
    out[512 + (size_t)row * 512 + tid] = v;
  }
}

extern "C" void kernel_launch(void* const* d_in, const int* in_sizes, int n_in,
                              void* d_out, int out_size, void* d_ws, size_t ws_size,
                              hipStream_t stream) {
  const float* x    = (const float*)d_in[0];
  const float* h0   = (const float*)d_in[1];
  const float* f1w0 = (const float*)d_in[2];
  const float* f1b0 = (const float*)d_in[3];
  const float* f2w0 = (const float*)d_in[4];
  const float* f2b0 = (const float*)d_in[5];
  const float* taw0 = (const float*)d_in[6];
  const float* tab0 = (const float*)d_in[7];
  const float* tbw0 = (const float*)d_in[8];
  const float* tbb0 = (const float*)d_in[9];
  const int*   m0   = (const int*)d_in[10];
  const float* f1w1 = (const float*)d_in[11];
  const float* f1b1 = (const float*)d_in[12];
  const float* f2w1 = (const float*)d_in[13];
  const float* f2b1 = (const float*)d_in[14];
  const float* taw1 = (const float*)d_in[15];
  const float* tab1 = (const float*)d_in[16];
  const float* tbw1 = (const float*)d_in[17];
  const float* tbb1 = (const float*)d_in[18];
  const int*   m1   = (const int*)d_in[19];
  const float* f1w2 = (const float*)d_in[20];
  const float* f1b2 = (const float*)d_in[21];
  const float* f2w2 = (const float*)d_in[22];
  const float* f2b2 = (const float*)d_in[23];
  const float* taw2 = (const float*)d_in[24];
  const float* tab2 = (const float*)d_in[25];
  const float* tbw2 = (const float*)d_in[26];
  const float* tbb2 = (const float*)d_in[27];
  const int*   m2   = (const int*)d_in[28];
  const float* fcw  = (const float*)d_in[29];
  const float* fcb  = (const float*)d_in[30];

  float* ws  = (float*)d_ws;
  float* out = (float*)d_out;

  // prep items: 176256 + 156672 + 416 + 306 + 204 + 2 = 333,856
  prep_kernel<<<1305, 256, 0, stream>>>(
      f1w0, f2w0, taw0, tbw0, m0, f1b0, f2b0, tab0, tbb0,
      f1w1, f2w1, taw1, tbw1, m1, f1b1, f2b1, tab1, tbb1,
      f1w2, f2w2, taw2, tbw2, m2, f1b2, f2b2, tab2, tbb2,
      ws);

  lnn_main<<<256, 1024, 0, stream>>>(x, h0, fcw, fcb, ws, out);
}